// Round 1
// baseline (438.879 us; speedup 1.0000x reference)
//
#include <hip/hip_runtime.h>
#include <hip/hip_bf16.h>
#include <math.h>

#define B_       512
#define SEQ_     25
#define C_       512
#define W_       5
#define BS_      2560          // B_*W_ rows per input
#define N_       5120          // 2*BS_
#define TEMP_INV 10.0f
#define EPS_     1e-8f

#define BM 64
#define BN 64
#define BK 32
#define PAD 4                  // +4 floats: keeps As[k][ty*4] 16B-aligned for ds_read_b128

// ---------------- kernel 1: adaptive-avg-pool (5-wide bins) + L2 normalize ----
__global__ __launch_bounds__(256) void pool_norm_kernel(const float* __restrict__ zi,
                                                        const float* __restrict__ zj,
                                                        float* __restrict__ zn) {
    int row = blockIdx.x;                       // 0..N_-1
    const float* src = (row < BS_) ? zi : zj;
    int rr = (row < BS_) ? row : row - BS_;
    int b = rr / W_;
    int w = rr - b * W_;
    const float* base = src + ((size_t)b * SEQ_ + (size_t)w * W_) * C_;
    int tid = threadIdx.x;
    int c0 = tid, c1 = tid + 256;
    float v0 = 0.f, v1 = 0.f;
#pragma unroll
    for (int t = 0; t < W_; ++t) {
        v0 += base[(size_t)t * C_ + c0];
        v1 += base[(size_t)t * C_ + c1];
    }
    v0 *= (1.0f / W_);
    v1 *= (1.0f / W_);
    float ss = v0 * v0 + v1 * v1;
#pragma unroll
    for (int m = 32; m >= 1; m >>= 1) ss += __shfl_xor(ss, m, 64);
    __shared__ float part[4];
    __shared__ float inv_s;
    int lane = tid & 63, wid = tid >> 6;
    if (lane == 0) part[wid] = ss;
    __syncthreads();
    if (tid == 0) {
        float nrm = sqrtf(part[0] + part[1] + part[2] + part[3]);
        inv_s = 1.0f / fmaxf(nrm, EPS_);
    }
    __syncthreads();
    float inv = inv_s;
    zn[(size_t)row * C_ + c0] = v0 * inv;
    zn[(size_t)row * C_ + c1] = v1 * inv;
}

// ---------------- kernel 2: 64x64 tile of sim, fused exp/mask/pos, row sums ---
__global__ __launch_bounds__(256) void simexp_kernel(const float* __restrict__ zn,
                                                     float* __restrict__ S,
                                                     float* __restrict__ pos) {
    __shared__ float As[BK][BM + PAD];
    __shared__ float Bs[BK][BN + PAD];
    int rt = blockIdx.x, ct = blockIdx.y;
    int tid = threadIdx.x;
    int tx = tid & 15, ty = tid >> 4;           // 16x16 thread grid, 4x4 microtile
    float acc[4][4] = {};
    const float* Abase = zn + (size_t)rt * BM * C_;
    const float* Bbase = zn + (size_t)ct * BN * C_;

    for (int k0 = 0; k0 < C_; k0 += BK) {
#pragma unroll
        for (int p = 0; p < 2; ++p) {
            int idx = tid + p * 256;            // 512 float4 slots per operand tile
            int r = idx >> 3;                   // 8 float4 per 32-wide k row
            int kk = (idx & 7) * 4;
            float4 a = *(const float4*)(Abase + (size_t)r * C_ + k0 + kk);
            As[kk + 0][r] = a.x; As[kk + 1][r] = a.y;
            As[kk + 2][r] = a.z; As[kk + 3][r] = a.w;
            float4 b = *(const float4*)(Bbase + (size_t)r * C_ + k0 + kk);
            Bs[kk + 0][r] = b.x; Bs[kk + 1][r] = b.y;
            Bs[kk + 2][r] = b.z; Bs[kk + 3][r] = b.w;
        }
        __syncthreads();
#pragma unroll
        for (int k = 0; k < BK; ++k) {
            float a[4], bb[4];
#pragma unroll
            for (int i = 0; i < 4; ++i) a[i] = As[k][ty * 4 + i];
#pragma unroll
            for (int j = 0; j < 4; ++j) bb[j] = Bs[k][tx * 4 + j];
#pragma unroll
            for (int i = 0; i < 4; ++i)
#pragma unroll
                for (int j = 0; j < 4; ++j)
                    acc[i][j] = fmaf(a[i], bb[j], acc[i][j]);
        }
        __syncthreads();
    }

    // epilogue: logits, exp, diagonal mask, pos capture, per-row reduce
#pragma unroll
    for (int i = 0; i < 4; ++i) {
        int rg = rt * BM + ty * 4 + i;
        int partner = (rg < BS_) ? rg + BS_ : rg - BS_;
        float s = 0.f;
#pragma unroll
        for (int j = 0; j < 4; ++j) {
            int cg = ct * BN + tx * 4 + j;
            float logit = acc[i][j] * TEMP_INV;
            float e = __expf(logit);
            if (cg == rg) e = 0.f;              // mask diagonal
            if (cg == partner) pos[rg] = logit; // unique writer
            s += e;
        }
        // reduce across the 16 tx lanes (contiguous within the wave)
        s += __shfl_xor(s, 1, 64);
        s += __shfl_xor(s, 2, 64);
        s += __shfl_xor(s, 4, 64);
        s += __shfl_xor(s, 8, 64);
        if (tx == 0) atomicAdd(&S[rg], s);
    }
}

// ---------------- kernel 3: loss = sum(log(S) - pos) / N ----------------------
__global__ __launch_bounds__(256) void loss_kernel(const float* __restrict__ S,
                                                   const float* __restrict__ pos,
                                                   float* __restrict__ out) {
    int tid = threadIdx.x;
    float acc = 0.f;
    for (int i = tid; i < N_; i += 256) acc += logf(S[i]) - pos[i];
#pragma unroll
    for (int m = 32; m >= 1; m >>= 1) acc += __shfl_xor(acc, m, 64);
    __shared__ float part[4];
    int lane = tid & 63, wid = tid >> 6;
    if (lane == 0) part[wid] = acc;
    __syncthreads();
    if (tid == 0) out[0] = (part[0] + part[1] + part[2] + part[3]) / (float)N_;
}

extern "C" void kernel_launch(void* const* d_in, const int* in_sizes, int n_in,
                              void* d_out, int out_size, void* d_ws, size_t ws_size,
                              hipStream_t stream) {
    const float* zi = (const float*)d_in[0];
    const float* zj = (const float*)d_in[1];
    float* out = (float*)d_out;

    char* ws = (char*)d_ws;
    float* zn  = (float*)ws;                                    // N_*C_ floats = 10.49 MB
    float* S   = (float*)(ws + (size_t)N_ * C_ * sizeof(float));// N_ floats
    float* pos = S + N_;                                        // N_ floats

    hipMemsetAsync(S, 0, N_ * sizeof(float), stream);
    pool_norm_kernel<<<N_, 256, 0, stream>>>(zi, zj, zn);
    dim3 grid(N_ / BM, N_ / BN);
    simexp_kernel<<<grid, 256, 0, stream>>>(zn, S, pos);
    loss_kernel<<<1, 256, 0, stream>>>(S, pos, out);
}

// Round 2
// 138.623 us; speedup vs baseline: 3.1660x; 3.1660x over previous
//
#include <hip/hip_runtime.h>
#include <hip/hip_bf16.h>
#include <math.h>

#define B_       512
#define SEQ_     25
#define C_       512
#define W_       5
#define BS_      2560          // B_*W_ rows per input
#define N_       5120          // 2*BS_
#define TEMP_INV 10.0f
#define EPS_     1e-8f

typedef __attribute__((ext_vector_type(8))) short short8;
typedef __attribute__((ext_vector_type(4))) float floatx4;

#define GAS(p) ((__attribute__((address_space(1))) void*)(void*)(p))
#define LAS(p) ((__attribute__((address_space(3))) void*)(p))

// ---------------- kernel 1: pool (5-wide bins) + L2 normalize + bf16 cast ----
__global__ __launch_bounds__(256) void pool_norm_kernel(const float* __restrict__ zi,
                                                        const float* __restrict__ zj,
                                                        __hip_bfloat16* __restrict__ zn) {
    int row = blockIdx.x;                       // 0..N_-1
    const float* src = (row < BS_) ? zi : zj;
    int rr = (row < BS_) ? row : row - BS_;
    int b = rr / W_;
    int w = rr - b * W_;
    const float* base = src + ((size_t)b * SEQ_ + (size_t)w * W_) * C_;
    int tid = threadIdx.x;
    int c0 = tid, c1 = tid + 256;
    float v0 = 0.f, v1 = 0.f;
#pragma unroll
    for (int t = 0; t < W_; ++t) {
        v0 += base[(size_t)t * C_ + c0];
        v1 += base[(size_t)t * C_ + c1];
    }
    v0 *= (1.0f / W_);
    v1 *= (1.0f / W_);
    float ss = v0 * v0 + v1 * v1;
#pragma unroll
    for (int m = 32; m >= 1; m >>= 1) ss += __shfl_xor(ss, m, 64);
    __shared__ float part[4];
    __shared__ float inv_s;
    int lane = tid & 63, wid = tid >> 6;
    if (lane == 0) part[wid] = ss;
    __syncthreads();
    if (tid == 0) {
        float nrm = sqrtf(part[0] + part[1] + part[2] + part[3]);
        inv_s = 1.0f / fmaxf(nrm, EPS_);
    }
    __syncthreads();
    float inv = inv_s;
    zn[(size_t)row * C_ + c0] = __float2bfloat16(v0 * inv);
    zn[(size_t)row * C_ + c1] = __float2bfloat16(v1 * inv);
}

// ---------------- kernel 2: 128x128 MFMA tile, fused exp/mask/pos, row sums --
// 4 waves, each wave owns a 64x64 quadrant = 4x4 grid of 16x16x32 bf16 MFMAs.
// LDS: A/B tiles 128 rows x 32 k (bf16), k-chunks XOR-swizzled by (row&3) to
// reduce ds_read_b128 bank aliasing. Swizzle is applied on the GLOBAL address
// inside global_load_lds (LDS side must stay lane-contiguous).
__global__ __launch_bounds__(256) void simexp_mfma(const ushort* __restrict__ zn,
                                                   float* __restrict__ S,
                                                   float* __restrict__ pos) {
    __shared__ __align__(16) ushort As[128 * 32];
    __shared__ __align__(16) ushort Bs[128 * 32];
    int tid = threadIdx.x;
    int wid = tid >> 6, lane = tid & 63;
    int rt = blockIdx.x, ct = blockIdx.y;
    int lrow = lane >> 2, lk = lane & 3;        // staging: 16 rows/chunk, 4 x 16B per row
    int lx = lane & 15, quad = lane >> 4;       // mfma fragment indexing
    int wrow = (wid >> 1) * 64, wcol = (wid & 1) * 64;

    // staging addresses: wave wid covers chunks {wid, wid+4} (16 rows each)
    int r0 = wid * 16 + lrow;
    int r1 = (wid + 4) * 16 + lrow;
    const ushort* gA0 = zn + (size_t)(rt * 128 + r0) * C_ + (lk ^ (r0 & 3)) * 8;
    const ushort* gA1 = zn + (size_t)(rt * 128 + r1) * C_ + (lk ^ (r1 & 3)) * 8;
    const ushort* gB0 = zn + (size_t)(ct * 128 + r0) * C_ + (lk ^ (r0 & 3)) * 8;
    const ushort* gB1 = zn + (size_t)(ct * 128 + r1) * C_ + (lk ^ (r1 & 3)) * 8;
    ushort* lA0 = As + wid * 512;               // HW appends lane*16 bytes
    ushort* lA1 = As + (wid + 4) * 512;
    ushort* lB0 = Bs + wid * 512;
    ushort* lB1 = Bs + (wid + 4) * 512;

    floatx4 acc[4][4] = {};

    for (int k0 = 0; k0 < C_; k0 += 32) {
        __builtin_amdgcn_global_load_lds(GAS(gA0 + k0), LAS(lA0), 16, 0, 0);
        __builtin_amdgcn_global_load_lds(GAS(gA1 + k0), LAS(lA1), 16, 0, 0);
        __builtin_amdgcn_global_load_lds(GAS(gB0 + k0), LAS(lB0), 16, 0, 0);
        __builtin_amdgcn_global_load_lds(GAS(gB1 + k0), LAS(lB1), 16, 0, 0);
        __syncthreads();

        short8 af[4], bf[4];
#pragma unroll
        for (int t = 0; t < 4; ++t) {
            int m = wrow + t * 16 + lx;
            af[t] = *(const short8*)&As[m * 32 + ((quad ^ (m & 3)) * 8)];
            int n = wcol + t * 16 + lx;
            bf[t] = *(const short8*)&Bs[n * 32 + ((quad ^ (n & 3)) * 8)];
        }
#pragma unroll
        for (int i = 0; i < 4; ++i)
#pragma unroll
            for (int j = 0; j < 4; ++j)
                acc[i][j] = __builtin_amdgcn_mfma_f32_16x16x32_bf16(af[i], bf[j], acc[i][j], 0, 0, 0);
        __syncthreads();
    }

    // epilogue: D layout col=lane&15, row=quad*4+reg (m89-verified)
    int colb = ct * 128 + wcol + lx;
#pragma unroll
    for (int i = 0; i < 4; ++i) {
#pragma unroll
        for (int r = 0; r < 4; ++r) {
            int m = rt * 128 + wrow + i * 16 + quad * 4 + r;
            int partner = (m < BS_) ? m + BS_ : m - BS_;
            float s = 0.f;
#pragma unroll
            for (int j = 0; j < 4; ++j) {
                int cg = colb + j * 16;
                float logit = acc[i][j][r] * TEMP_INV;
                float e = __expf(logit);
                if (cg == m) e = 0.f;               // mask diagonal
                if (cg == partner) pos[m] = logit;  // unique writer
                s += e;
            }
            s += __shfl_xor(s, 1, 64);
            s += __shfl_xor(s, 2, 64);
            s += __shfl_xor(s, 4, 64);
            s += __shfl_xor(s, 8, 64);
            if (lx == 0) atomicAdd(&S[m], s);
        }
    }
}

// ---------------- kernel 3: loss = sum(log(S) - pos) / N ---------------------
__global__ __launch_bounds__(256) void loss_kernel(const float* __restrict__ S,
                                                   const float* __restrict__ pos,
                                                   float* __restrict__ out) {
    int tid = threadIdx.x;
    float acc = 0.f;
    for (int i = tid; i < N_; i += 256) acc += logf(S[i]) - pos[i];
#pragma unroll
    for (int m = 32; m >= 1; m >>= 1) acc += __shfl_xor(acc, m, 64);
    __shared__ float part[4];
    int lane = tid & 63, wid = tid >> 6;
    if (lane == 0) part[wid] = acc;
    __syncthreads();
    if (tid == 0) out[0] = (part[0] + part[1] + part[2] + part[3]) / (float)N_;
}

extern "C" void kernel_launch(void* const* d_in, const int* in_sizes, int n_in,
                              void* d_out, int out_size, void* d_ws, size_t ws_size,
                              hipStream_t stream) {
    const float* zi = (const float*)d_in[0];
    const float* zj = (const float*)d_in[1];
    float* out = (float*)d_out;

    char* ws = (char*)d_ws;
    __hip_bfloat16* zn = (__hip_bfloat16*)ws;                   // N_*C_ bf16 = 5.24 MB
    float* S   = (float*)(ws + (size_t)N_ * C_ * sizeof(__hip_bfloat16));
    float* pos = S + N_;

    hipMemsetAsync(S, 0, N_ * sizeof(float), stream);
    pool_norm_kernel<<<N_, 256, 0, stream>>>(zi, zj, zn);
    dim3 grid(N_ / 128, N_ / 128);
    simexp_mfma<<<grid, 256, 0, stream>>>((const ushort*)zn, S, pos);
    loss_kernel<<<1, 256, 0, stream>>>(S, pos, out);
}

// Round 3
// 120.870 us; speedup vs baseline: 3.6310x; 1.1469x over previous
//
#include <hip/hip_runtime.h>
#include <hip/hip_bf16.h>
#include <math.h>

#define B_       512
#define SEQ_     25
#define C_       512
#define W_       5
#define BS_      2560          // B_*W_ rows per input
#define N_       5120          // 2*BS_
#define NT_      40            // N_/128 tile rows
#define TEMP_INV 10.0f
#define EPS_     1e-8f

typedef __attribute__((ext_vector_type(8))) short short8;
typedef __attribute__((ext_vector_type(4))) float floatx4;

#define GAS(p) ((__attribute__((address_space(1))) void*)(void*)(p))
#define LAS(p) ((__attribute__((address_space(3))) void*)(p))

static __device__ __forceinline__ ushort f2bf(float f) {
    __hip_bfloat16 h = __float2bfloat16(f);
    return *(ushort*)&h;
}

// ---- kernel 1: pool (5-wide bins) + L2 normalize + bf16 cast + S zeroing ----
// One wave per output row, float4 loads, butterfly reduce — no barriers.
__global__ __launch_bounds__(256) void pool_norm_kernel(const float* __restrict__ zi,
                                                        const float* __restrict__ zj,
                                                        ushort* __restrict__ zn,
                                                        float* __restrict__ S) {
    int row = blockIdx.x * 4 + (threadIdx.x >> 6);
    int lane = threadIdx.x & 63;
    const float* src = (row < BS_) ? zi : zj;
    int rr = (row < BS_) ? row : row - BS_;
    int b = rr / W_;
    int w = rr - b * W_;
    const float4* base4 = (const float4*)(src + ((size_t)b * SEQ_ + (size_t)w * W_) * C_);
    float4 v0 = {0, 0, 0, 0}, v1 = {0, 0, 0, 0};
#pragma unroll
    for (int t = 0; t < W_; ++t) {
        float4 a = base4[t * 128 + lane];
        float4 c = base4[t * 128 + 64 + lane];
        v0.x += a.x; v0.y += a.y; v0.z += a.z; v0.w += a.w;
        v1.x += c.x; v1.y += c.y; v1.z += c.z; v1.w += c.w;
    }
    const float s5 = 1.0f / W_;
    v0.x *= s5; v0.y *= s5; v0.z *= s5; v0.w *= s5;
    v1.x *= s5; v1.y *= s5; v1.z *= s5; v1.w *= s5;
    float ss = v0.x * v0.x + v0.y * v0.y + v0.z * v0.z + v0.w * v0.w
             + v1.x * v1.x + v1.y * v1.y + v1.z * v1.z + v1.w * v1.w;
#pragma unroll
    for (int m = 32; m >= 1; m >>= 1) ss += __shfl_xor(ss, m, 64);
    float inv = 1.0f / fmaxf(sqrtf(ss), EPS_);
    ushort4 o0, o1;
    o0.x = f2bf(v0.x * inv); o0.y = f2bf(v0.y * inv);
    o0.z = f2bf(v0.z * inv); o0.w = f2bf(v0.w * inv);
    o1.x = f2bf(v1.x * inv); o1.y = f2bf(v1.y * inv);
    o1.z = f2bf(v1.z * inv); o1.w = f2bf(v1.w * inv);
    *(ushort4*)(zn + (size_t)row * C_ + lane * 4) = o0;
    *(ushort4*)(zn + (size_t)row * C_ + 256 + lane * 4) = o1;
    if (lane == 0) S[row] = 0.f;   // replaces the memset launch
}

// ---- kernel 2: upper-triangle 128x128 MFMA tiles, fused exp/mask/pos --------
// 4 waves x (4x4 of 16x16x32 bf16 MFMA), BK=64, global_load_lds width=16.
// Off-diagonal tiles contribute row sums AND column sums (symmetry).
__global__ __launch_bounds__(256) void simexp_mfma(const ushort* __restrict__ zn,
                                                   float* __restrict__ S,
                                                   float* __restrict__ pos) {
    __shared__ __align__(16) ushort As[128 * 64];
    __shared__ __align__(16) ushort Bs[128 * 64];
    // decode upper-triangle tile index (scalar, uniform)
    int t = blockIdx.x, rt = 0, rem = NT_;
    while (t >= rem) { t -= rem; rem--; rt++; }
    int ct = rt + t;

    int tid = threadIdx.x;
    int wid = tid >> 6, lane = tid & 63;
    int lrow = lane >> 3, lk = lane & 7;        // staging: 8 rows x 8 chunks of 16B
    int lx = lane & 15, quad = lane >> 4;       // mfma fragment indexing
    int wrow = (wid >> 1) * 64, wcol = (wid & 1) * 64;
    int swz = lk ^ lrow;                        // k-chunk swizzle (row&7 == lrow)

    const ushort* gA[4]; const ushort* gB[4];
    ushort* lA[4]; ushort* lB[4];
#pragma unroll
    for (int c = 0; c < 4; ++c) {
        int r = wid * 32 + c * 8 + lrow;
        gA[c] = zn + (size_t)(rt * 128 + r) * C_ + swz * 8;
        gB[c] = zn + (size_t)(ct * 128 + r) * C_ + swz * 8;
        lA[c] = As + (wid * 32 + c * 8) * 64;   // HW appends lane*16B
        lB[c] = Bs + (wid * 32 + c * 8) * 64;
    }

    floatx4 acc[4][4] = {};

    for (int k0 = 0; k0 < C_; k0 += 64) {
#pragma unroll
        for (int c = 0; c < 4; ++c) {
            __builtin_amdgcn_global_load_lds(GAS(gA[c] + k0), LAS(lA[c]), 16, 0, 0);
            __builtin_amdgcn_global_load_lds(GAS(gB[c] + k0), LAS(lB[c]), 16, 0, 0);
        }
        __syncthreads();
#pragma unroll
        for (int ks = 0; ks < 2; ++ks) {
            short8 af[4], bf[4];
#pragma unroll
            for (int tt = 0; tt < 4; ++tt) {
                int m = wrow + tt * 16 + lx;
                af[tt] = *(const short8*)&As[m * 64 + (((ks * 4 + quad) ^ (lx & 7)) * 8)];
                int n = wcol + tt * 16 + lx;
                bf[tt] = *(const short8*)&Bs[n * 64 + (((ks * 4 + quad) ^ (lx & 7)) * 8)];
            }
#pragma unroll
            for (int i = 0; i < 4; ++i)
#pragma unroll
                for (int j = 0; j < 4; ++j)
                    acc[i][j] = __builtin_amdgcn_mfma_f32_16x16x32_bf16(af[i], bf[j], acc[i][j], 0, 0, 0);
        }
        __syncthreads();
    }

    // epilogue: D layout col=lane&15, row=quad*4+reg (m89-verified)
    int colb = ct * 128 + wcol + lx;
    if (rt == ct) {
        // diagonal tile: mask diagonal, row sums only (pos never here)
#pragma unroll
        for (int i = 0; i < 4; ++i) {
#pragma unroll
            for (int r = 0; r < 4; ++r) {
                int m = rt * 128 + wrow + i * 16 + quad * 4 + r;
                float s = 0.f;
#pragma unroll
                for (int j = 0; j < 4; ++j) {
                    int cg = colb + j * 16;
                    float e = __expf(acc[i][j][r] * TEMP_INV);
                    if (cg == m) e = 0.f;
                    s += e;
                }
                s += __shfl_xor(s, 1, 64);
                s += __shfl_xor(s, 2, 64);
                s += __shfl_xor(s, 4, 64);
                s += __shfl_xor(s, 8, 64);
                if (lx == 0) atomicAdd(&S[m], s);
            }
        }
    } else {
        // off-diagonal: row sums + column sums (transposed half), pos capture
        float colpart[4] = {0.f, 0.f, 0.f, 0.f};
#pragma unroll
        for (int i = 0; i < 4; ++i) {
#pragma unroll
            for (int r = 0; r < 4; ++r) {
                int m = rt * 128 + wrow + i * 16 + quad * 4 + r;
                int partner = m + BS_;          // only m<BS_ can hit in upper triangle
                float s = 0.f;
#pragma unroll
                for (int j = 0; j < 4; ++j) {
                    int cg = colb + j * 16;
                    float logit = acc[i][j][r] * TEMP_INV;
                    float e = __expf(logit);
                    if (cg == partner) { pos[m] = logit; pos[cg] = logit; }
                    s += e;
                    colpart[j] += e;
                }
                s += __shfl_xor(s, 1, 64);
                s += __shfl_xor(s, 2, 64);
                s += __shfl_xor(s, 4, 64);
                s += __shfl_xor(s, 8, 64);
                if (lx == 0) atomicAdd(&S[m], s);
            }
        }
#pragma unroll
        for (int j = 0; j < 4; ++j) {
            float cs = colpart[j];
            cs += __shfl_xor(cs, 16, 64);
            cs += __shfl_xor(cs, 32, 64);
            if (quad == 0) atomicAdd(&S[colb + j * 16], cs);
        }
    }
}

// ---- kernel 3: loss = sum(log(S) - pos) / N ---------------------------------
__global__ __launch_bounds__(256) void loss_kernel(const float* __restrict__ S,
                                                   const float* __restrict__ pos,
                                                   float* __restrict__ out) {
    int tid = threadIdx.x;
    float acc = 0.f;
    for (int i = tid; i < N_; i += 256) acc += logf(S[i]) - pos[i];
#pragma unroll
    for (int m = 32; m >= 1; m >>= 1) acc += __shfl_xor(acc, m, 64);
    __shared__ float part[4];
    int lane = tid & 63, wid = tid >> 6;
    if (lane == 0) part[wid] = acc;
    __syncthreads();
    if (tid == 0) out[0] = (part[0] + part[1] + part[2] + part[3]) / (float)N_;
}

extern "C" void kernel_launch(void* const* d_in, const int* in_sizes, int n_in,
                              void* d_out, int out_size, void* d_ws, size_t ws_size,
                              hipStream_t stream) {
    const float* zi = (const float*)d_in[0];
    const float* zj = (const float*)d_in[1];
    float* out = (float*)d_out;

    char* ws = (char*)d_ws;
    ushort* zn = (ushort*)ws;                                   // N_*C_ bf16 = 5.24 MB
    float* S   = (float*)(ws + (size_t)N_ * C_ * sizeof(ushort));
    float* pos = S + N_;

    pool_norm_kernel<<<N_ / 4, 256, 0, stream>>>(zi, zj, zn, S);
    int ntiles = NT_ * (NT_ + 1) / 2;                           // 820 upper-tri tiles
    simexp_mfma<<<ntiles, 256, 0, stream>>>(zn, S, pos);
    loss_kernel<<<1, 256, 0, stream>>>(S, pos, out);
}

// Round 4
// 107.288 us; speedup vs baseline: 4.0907x; 1.1266x over previous
//
#include <hip/hip_runtime.h>
#include <hip/hip_bf16.h>
#include <math.h>

#define B_       512
#define SEQ_     25
#define C_       512
#define W_       5
#define BS_      2560          // B_*W_ rows per input
#define N_       5120          // 2*BS_
#define NT_      40            // N_/128 tile rows
#define CB_      512           // bytes per zn row (512 fp8)
#define TEMP_INV 10.0f
#define EPS_     1e-8f

typedef __attribute__((ext_vector_type(4))) int   int4v;
typedef __attribute__((ext_vector_type(8))) int   int8v;
typedef __attribute__((ext_vector_type(4))) float floatx4;

#define GAS(p) ((__attribute__((address_space(1))) void*)(void*)(p))
#define LAS(p) ((__attribute__((address_space(3))) void*)(p))

// ---- kernel 1: pool (5-wide bins) + L2 normalize + fp8(e4m3) cast -----------
// One wave per output row, float4 loads, butterfly reduce. Also zeroes S/out.
__global__ __launch_bounds__(256) void pool_norm_kernel(const float* __restrict__ zi,
                                                        const float* __restrict__ zj,
                                                        uint* __restrict__ zn8,
                                                        float* __restrict__ S,
                                                        float* __restrict__ out) {
    int row = blockIdx.x * 4 + (threadIdx.x >> 6);
    int lane = threadIdx.x & 63;
    const float* src = (row < BS_) ? zi : zj;
    int rr = (row < BS_) ? row : row - BS_;
    int b = rr / W_;
    int w = rr - b * W_;
    const float4* base4 = (const float4*)(src + ((size_t)b * SEQ_ + (size_t)w * W_) * C_);
    float4 v0 = {0, 0, 0, 0}, v1 = {0, 0, 0, 0};
#pragma unroll
    for (int t = 0; t < W_; ++t) {
        float4 a = base4[t * 128 + lane];
        float4 c = base4[t * 128 + 64 + lane];
        v0.x += a.x; v0.y += a.y; v0.z += a.z; v0.w += a.w;
        v1.x += c.x; v1.y += c.y; v1.z += c.z; v1.w += c.w;
    }
    float ss = v0.x * v0.x + v0.y * v0.y + v0.z * v0.z + v0.w * v0.w
             + v1.x * v1.x + v1.y * v1.y + v1.z * v1.z + v1.w * v1.w;
#pragma unroll
    for (int m = 32; m >= 1; m >>= 1) ss += __shfl_xor(ss, m, 64);
    // note: 1/5 pooling scale folded into 1/norm (scale-invariant cosine)
    float inv = 1.0f / fmaxf(sqrtf(ss), EPS_);
    uint p0 = __builtin_amdgcn_cvt_pk_fp8_f32(v0.x * inv, v0.y * inv, 0, false);
    p0      = __builtin_amdgcn_cvt_pk_fp8_f32(v0.z * inv, v0.w * inv, p0, true);
    uint p1 = __builtin_amdgcn_cvt_pk_fp8_f32(v1.x * inv, v1.y * inv, 0, false);
    p1      = __builtin_amdgcn_cvt_pk_fp8_f32(v1.z * inv, v1.w * inv, p1, true);
    zn8[(size_t)row * 128 + lane]      = p0;
    zn8[(size_t)row * 128 + 64 + lane] = p1;
    if (lane == 0) S[row] = 0.f;                    // replaces memset launch
    if (row == 0 && lane == 0) out[0] = 0.f;        // loss accumulator init
}

// ---- kernel 2: upper-triangle 128x128 tiles, MX-fp8 K=128 MFMA --------------
// 4 waves x (4x4 of mfma_scale_f32_16x16x128_f8f6f4, scales=1.0). BK=128 fp8
// bytes -> only 4 K-iterations. 16B k-chunks XOR-swizzled by (row&7).
__global__ __launch_bounds__(256) void simexp_mfma(const unsigned char* __restrict__ zn,
                                                   float* __restrict__ S,
                                                   float* __restrict__ pos) {
    __shared__ __align__(16) unsigned char As[128 * 128];
    __shared__ __align__(16) unsigned char Bs[128 * 128];
    // decode upper-triangle tile index (scalar, uniform)
    int t = blockIdx.x, rt = 0, rem = NT_;
    while (t >= rem) { t -= rem; rem--; rt++; }
    int ct = rt + t;

    int tid = threadIdx.x;
    int wid = tid >> 6, lane = tid & 63;
    int lrow = lane >> 3, lk = lane & 7;        // staging: 8 rows x 8 chunks of 16B
    int lx = lane & 15, quad = lane >> 4, sx = lx & 7;
    int wrow = (wid >> 1) * 64, wcol = (wid & 1) * 64;

    const unsigned char* gA[4]; const unsigned char* gB[4];
    unsigned char* lA[4]; unsigned char* lB[4];
#pragma unroll
    for (int c = 0; c < 4; ++c) {
        int r = wid * 32 + c * 8 + lrow;
        gA[c] = zn + (size_t)(rt * 128 + r) * CB_ + (lk ^ lrow) * 16;
        gB[c] = zn + (size_t)(ct * 128 + r) * CB_ + (lk ^ lrow) * 16;
        lA[c] = As + (wid * 32 + c * 8) * 128;  // HW appends lane*16B
        lB[c] = Bs + (wid * 32 + c * 8) * 128;
    }

    union frag { int8v v8; int4v v4[2]; };
    floatx4 acc[4][4] = {};

    for (int k0 = 0; k0 < CB_; k0 += 128) {
#pragma unroll
        for (int c = 0; c < 4; ++c) {
            __builtin_amdgcn_global_load_lds(GAS(gA[c] + k0), LAS(lA[c]), 16, 0, 0);
            __builtin_amdgcn_global_load_lds(GAS(gB[c] + k0), LAS(lB[c]), 16, 0, 0);
        }
        __syncthreads();

        frag af[4], bf[4];
#pragma unroll
        for (int tt = 0; tt < 4; ++tt) {
            int m = wrow + tt * 16 + lx;
            af[tt].v4[0] = *(const int4v*)&As[m * 128 + (((quad * 2    ) ^ sx) * 16)];
            af[tt].v4[1] = *(const int4v*)&As[m * 128 + (((quad * 2 + 1) ^ sx) * 16)];
            int n = wcol + tt * 16 + lx;
            bf[tt].v4[0] = *(const int4v*)&Bs[n * 128 + (((quad * 2    ) ^ sx) * 16)];
            bf[tt].v4[1] = *(const int4v*)&Bs[n * 128 + (((quad * 2 + 1) ^ sx) * 16)];
        }
#pragma unroll
        for (int i = 0; i < 4; ++i)
#pragma unroll
            for (int j = 0; j < 4; ++j)
                acc[i][j] = __builtin_amdgcn_mfma_scale_f32_16x16x128_f8f6f4(
                    af[i].v8, bf[j].v8, acc[i][j],
                    0, 0,                    // cbsz=fp8(e4m3), blgp=fp8(e4m3)
                    0, 0x7f7f7f7f,           // scale A opsel, E8M0 1.0
                    0, 0x7f7f7f7f);          // scale B opsel, E8M0 1.0
        __syncthreads();
    }

    // epilogue: D layout col=lane&15, row=quad*4+reg (shape-determined, m121-128)
    int colb = ct * 128 + wcol + lx;
    if (rt == ct) {
        // diagonal tile: mask diagonal, row sums only (pos never here)
#pragma unroll
        for (int i = 0; i < 4; ++i) {
#pragma unroll
            for (int r = 0; r < 4; ++r) {
                int m = rt * 128 + wrow + i * 16 + quad * 4 + r;
                float s = 0.f;
#pragma unroll
                for (int j = 0; j < 4; ++j) {
                    int cg = colb + j * 16;
                    float e = __expf(acc[i][j][r] * TEMP_INV);
                    if (cg == m) e = 0.f;
                    s += e;
                }
                s += __shfl_xor(s, 1, 64);
                s += __shfl_xor(s, 2, 64);
                s += __shfl_xor(s, 4, 64);
                s += __shfl_xor(s, 8, 64);
                if (lx == 0) atomicAdd(&S[m], s);
            }
        }
    } else {
        // off-diagonal: row sums + column sums (transposed half), pos capture
        float colpart[4] = {0.f, 0.f, 0.f, 0.f};
#pragma unroll
        for (int i = 0; i < 4; ++i) {
#pragma unroll
            for (int r = 0; r < 4; ++r) {
                int m = rt * 128 + wrow + i * 16 + quad * 4 + r;
                int partner = m + BS_;          // only m<BS_ can hit in upper triangle
                float s = 0.f;
#pragma unroll
                for (int j = 0; j < 4; ++j) {
                    int cg = colb + j * 16;
                    float logit = acc[i][j][r] * TEMP_INV;
                    float e = __expf(logit);
                    if (cg == partner) { pos[m] = logit; pos[cg] = logit; }
                    s += e;
                    colpart[j] += e;
                }
                s += __shfl_xor(s, 1, 64);
                s += __shfl_xor(s, 2, 64);
                s += __shfl_xor(s, 4, 64);
                s += __shfl_xor(s, 8, 64);
                if (lx == 0) atomicAdd(&S[m], s);
            }
        }
#pragma unroll
        for (int j = 0; j < 4; ++j) {
            float cs = colpart[j];
            cs += __shfl_xor(cs, 16, 64);
            cs += __shfl_xor(cs, 32, 64);
            if (quad == 0) atomicAdd(&S[colb + j * 16], cs);
        }
    }
}

// ---- kernel 3: loss = sum(log(S) - pos) / N  (20 blocks, atomic accumulate) -
__global__ __launch_bounds__(256) void loss_kernel(const float* __restrict__ S,
                                                   const float* __restrict__ pos,
                                                   float* __restrict__ out) {
    int i = blockIdx.x * 256 + threadIdx.x;
    float a = logf(S[i]) - pos[i];
#pragma unroll
    for (int m = 32; m >= 1; m >>= 1) a += __shfl_xor(a, m, 64);
    __shared__ float part[4];
    int lane = threadIdx.x & 63, wid = threadIdx.x >> 6;
    if (lane == 0) part[wid] = a;
    __syncthreads();
    if (threadIdx.x == 0)
        atomicAdd(out, (part[0] + part[1] + part[2] + part[3]) * (1.0f / N_));
}

extern "C" void kernel_launch(void* const* d_in, const int* in_sizes, int n_in,
                              void* d_out, int out_size, void* d_ws, size_t ws_size,
                              hipStream_t stream) {
    const float* zi = (const float*)d_in[0];
    const float* zj = (const float*)d_in[1];
    float* out = (float*)d_out;

    char* ws = (char*)d_ws;
    unsigned char* zn = (unsigned char*)ws;                    // N_*512 fp8 = 2.62 MB
    float* S   = (float*)(ws + (size_t)N_ * CB_);
    float* pos = S + N_;

    pool_norm_kernel<<<N_ / 4, 256, 0, stream>>>(zi, zj, (uint*)zn, S, out);
    int ntiles = NT_ * (NT_ + 1) / 2;                          // 820 upper-tri tiles
    simexp_mfma<<<ntiles, 256, 0, stream>>>(zn, S, pos);
    loss_kernel<<<N_ / 256, 256, 0, stream>>>(S, pos, out);
}

// Round 5
// 106.952 us; speedup vs baseline: 4.1035x; 1.0031x over previous
//
#include <hip/hip_runtime.h>
#include <hip/hip_bf16.h>
#include <math.h>

#define B_       512
#define SEQ_     25
#define C_       512
#define W_       5
#define BS_      2560          // B_*W_ rows per input
#define N_       5120          // 2*BS_
#define NT_      40            // N_/128 tile rows
#define CB4_     256           // bytes per zn row (512 fp4 nibbles)
#define TEMP_INV 10.0f
#define EPS_     1e-8f

typedef __attribute__((ext_vector_type(4))) int   int4v;
typedef __attribute__((ext_vector_type(8))) int   int8v;
typedef __attribute__((ext_vector_type(4))) float floatx4;

#define GAS(p) ((__attribute__((address_space(1))) void*)(void*)(p))
#define LAS(p) ((__attribute__((address_space(3))) void*)(p))

// e2m1 quantize of x (pre-scaled by 32): codes 0..7 = {0,.5,1,1.5,2,3,4,6}
static __device__ __forceinline__ uint fp4q(float x) {
    float m = fabsf(x);
    uint c;
    if      (m < 0.25f) c = 0;
    else if (m < 0.75f) c = 1;
    else if (m < 1.25f) c = 2;
    else if (m < 1.75f) c = 3;
    else if (m < 2.5f)  c = 4;
    else if (m < 3.5f)  c = 5;
    else if (m < 5.0f)  c = 6;
    else                c = 7;
    return c | (x < 0.f ? 8u : 0u);
}

// ---- kernel 1: pool (5-wide bins) + L2 normalize + fp4(e2m1) pack -----------
// One wave per output row; each lane owns 8 contiguous channels -> one uint of
// 8 nibbles. Block scale 2^-5 folded here (x = v*inv*32), E8M0 0x7A in MFMA.
__global__ __launch_bounds__(256) void pool_norm_kernel(const float* __restrict__ zi,
                                                        const float* __restrict__ zj,
                                                        uint* __restrict__ zn4,
                                                        float* __restrict__ S,
                                                        float* __restrict__ out) {
    int row = blockIdx.x * 4 + (threadIdx.x >> 6);
    int lane = threadIdx.x & 63;
    const float* src = (row < BS_) ? zi : zj;
    int rr = (row < BS_) ? row : row - BS_;
    int b = rr / W_;
    int w = rr - b * W_;
    const float4* base4 = (const float4*)(src + ((size_t)b * SEQ_ + (size_t)w * W_) * C_);
    float4 v0 = {0, 0, 0, 0}, v1 = {0, 0, 0, 0};
#pragma unroll
    for (int t = 0; t < W_; ++t) {
        float4 a = base4[t * 128 + lane * 2];
        float4 c = base4[t * 128 + lane * 2 + 1];
        v0.x += a.x; v0.y += a.y; v0.z += a.z; v0.w += a.w;
        v1.x += c.x; v1.y += c.y; v1.z += c.z; v1.w += c.w;
    }
    float ss = v0.x * v0.x + v0.y * v0.y + v0.z * v0.z + v0.w * v0.w
             + v1.x * v1.x + v1.y * v1.y + v1.z * v1.z + v1.w * v1.w;
#pragma unroll
    for (int m = 32; m >= 1; m >>= 1) ss += __shfl_xor(ss, m, 64);
    // 1/5 pooling scale folds into 1/norm (cosine is scale-invariant)
    float inv32 = 32.0f / fmaxf(sqrtf(ss), EPS_);
    uint p = fp4q(v0.x * inv32);
    p |= fp4q(v0.y * inv32) << 4;
    p |= fp4q(v0.z * inv32) << 8;
    p |= fp4q(v0.w * inv32) << 12;
    p |= fp4q(v1.x * inv32) << 16;
    p |= fp4q(v1.y * inv32) << 20;
    p |= fp4q(v1.z * inv32) << 24;
    p |= fp4q(v1.w * inv32) << 28;
    zn4[(size_t)row * 64 + lane] = p;
    if (lane == 0) S[row] = 0.f;                    // replaces memset launch
    if (row == 0 && lane == 0) out[0] = 0.f;        // loss accumulator init
}

// ---- kernel 2: upper-triangle 128x128 tiles, MX-fp4 K=128 MFMA --------------
// 4 waves x (4x4 of mfma_scale_f32_16x16x128_f8f6f4, fmt=fp4, scale=2^-5).
// Per-iter staging: 64 B/row (4 x 16B chunks), chunk XOR (row&3) swizzle on
// the global side keeps both the DMA write and ds_read_b128 conflict-free.
__global__ __launch_bounds__(256) void simexp_mfma(const unsigned char* __restrict__ zn,
                                                   float* __restrict__ S,
                                                   float* __restrict__ pos) {
    __shared__ __align__(16) unsigned char As[128 * 64];
    __shared__ __align__(16) unsigned char Bs[128 * 64];
    // decode upper-triangle tile index (scalar, uniform)
    int t = blockIdx.x, rt = 0, rem = NT_;
    while (t >= rem) { t -= rem; rem--; rt++; }
    int ct = rt + t;

    int tid = threadIdx.x;
    int wid = tid >> 6, lane = tid & 63;
    int lrow = lane >> 2, lk = lane & 3;        // staging: 16 rows x 4 chunks of 16B
    int lx = lane & 15, quad = lane >> 4;       // mfma fragment indexing
    int wrow = (wid >> 1) * 64, wcol = (wid & 1) * 64;

    const unsigned char* gA[2]; const unsigned char* gB[2];
    unsigned char* lA[2]; unsigned char* lB[2];
#pragma unroll
    for (int c = 0; c < 2; ++c) {
        int r = wid * 32 + c * 16 + lrow;
        gA[c] = zn + (size_t)(rt * 128 + r) * CB4_ + ((lk ^ (lrow & 3)) * 16);
        gB[c] = zn + (size_t)(ct * 128 + r) * CB4_ + ((lk ^ (lrow & 3)) * 16);
        lA[c] = As + (wid * 32 + c * 16) * 64;  // HW appends lane*16B
        lB[c] = Bs + (wid * 32 + c * 16) * 64;
    }

    union frag { int8v v8; int4v v4[2]; };
    floatx4 acc[4][4] = {};

    for (int k0 = 0; k0 < CB4_; k0 += 64) {     // 4 iters, 128 K-elems each
#pragma unroll
        for (int c = 0; c < 2; ++c) {
            __builtin_amdgcn_global_load_lds(GAS(gA[c] + k0), LAS(lA[c]), 16, 0, 0);
            __builtin_amdgcn_global_load_lds(GAS(gB[c] + k0), LAS(lB[c]), 16, 0, 0);
        }
        __syncthreads();

        frag af[4], bf[4];
#pragma unroll
        for (int tt = 0; tt < 4; ++tt) {
            int m = wrow + tt * 16 + lx;
            af[tt].v4[0] = *(const int4v*)&As[m * 64 + ((quad ^ (m & 3)) * 16)];
            af[tt].v4[1] = (int4v)(0);
            int n = wcol + tt * 16 + lx;
            bf[tt].v4[0] = *(const int4v*)&Bs[n * 64 + ((quad ^ (n & 3)) * 16)];
            bf[tt].v4[1] = (int4v)(0);
        }
#pragma unroll
        for (int i = 0; i < 4; ++i)
#pragma unroll
            for (int j = 0; j < 4; ++j)
                acc[i][j] = __builtin_amdgcn_mfma_scale_f32_16x16x128_f8f6f4(
                    af[i].v8, bf[j].v8, acc[i][j],
                    4, 4,                    // cbsz=fp4(e2m1), blgp=fp4(e2m1)
                    0, 0x7A7A7A7A,           // scale A: E8M0 2^-5
                    0, 0x7A7A7A7A);          // scale B: E8M0 2^-5
        __syncthreads();
    }

    // epilogue: D layout col=lane&15, row=quad*4+reg (shape-determined)
    int colb = ct * 128 + wcol + lx;
    if (rt == ct) {
        // diagonal tile: mask diagonal, row sums only (pos never here)
#pragma unroll
        for (int i = 0; i < 4; ++i) {
#pragma unroll
            for (int r = 0; r < 4; ++r) {
                int m = rt * 128 + wrow + i * 16 + quad * 4 + r;
                float s = 0.f;
#pragma unroll
                for (int j = 0; j < 4; ++j) {
                    int cg = colb + j * 16;
                    float e = __expf(acc[i][j][r] * TEMP_INV);
                    if (cg == m) e = 0.f;
                    s += e;
                }
                s += __shfl_xor(s, 1, 64);
                s += __shfl_xor(s, 2, 64);
                s += __shfl_xor(s, 4, 64);
                s += __shfl_xor(s, 8, 64);
                if (lx == 0) atomicAdd(&S[m], s);
            }
        }
    } else {
        // off-diagonal: row sums + column sums (transposed half), pos capture
        float colpart[4] = {0.f, 0.f, 0.f, 0.f};
#pragma unroll
        for (int i = 0; i < 4; ++i) {
#pragma unroll
            for (int r = 0; r < 4; ++r) {
                int m = rt * 128 + wrow + i * 16 + quad * 4 + r;
                int partner = m + BS_;          // only m<BS_ can hit in upper triangle
                float s = 0.f;
#pragma unroll
                for (int j = 0; j < 4; ++j) {
                    int cg = colb + j * 16;
                    float logit = acc[i][j][r] * TEMP_INV;
                    float e = __expf(logit);
                    if (cg == partner) { pos[m] = logit; pos[cg] = logit; }
                    s += e;
                    colpart[j] += e;
                }
                s += __shfl_xor(s, 1, 64);
                s += __shfl_xor(s, 2, 64);
                s += __shfl_xor(s, 4, 64);
                s += __shfl_xor(s, 8, 64);
                if (lx == 0) atomicAdd(&S[m], s);
            }
        }
#pragma unroll
        for (int j = 0; j < 4; ++j) {
            float cs = colpart[j];
            cs += __shfl_xor(cs, 16, 64);
            cs += __shfl_xor(cs, 32, 64);
            if (quad == 0) atomicAdd(&S[colb + j * 16], cs);
        }
    }
}

// ---- kernel 3: loss = sum(log(S) - pos) / N  (20 blocks, atomic accumulate) -
__global__ __launch_bounds__(256) void loss_kernel(const float* __restrict__ S,
                                                   const float* __restrict__ pos,
                                                   float* __restrict__ out) {
    int i = blockIdx.x * 256 + threadIdx.x;
    float a = logf(S[i]) - pos[i];
#pragma unroll
    for (int m = 32; m >= 1; m >>= 1) a += __shfl_xor(a, m, 64);
    __shared__ float part[4];
    int lane = threadIdx.x & 63, wid = threadIdx.x >> 6;
    if (lane == 0) part[wid] = a;
    __syncthreads();
    if (threadIdx.x == 0)
        atomicAdd(out, (part[0] + part[1] + part[2] + part[3]) * (1.0f / N_));
}

extern "C" void kernel_launch(void* const* d_in, const int* in_sizes, int n_in,
                              void* d_out, int out_size, void* d_ws, size_t ws_size,
                              hipStream_t stream) {
    const float* zi = (const float*)d_in[0];
    const float* zj = (const float*)d_in[1];
    float* out = (float*)d_out;

    char* ws = (char*)d_ws;
    unsigned char* zn = (unsigned char*)ws;                    // N_*256 B fp4 = 1.31 MB
    float* S   = (float*)(ws + (size_t)N_ * CB4_);
    float* pos = S + N_;

    pool_norm_kernel<<<N_ / 4, 256, 0, stream>>>(zi, zj, (uint*)zn, S, out);
    int ntiles = NT_ * (NT_ + 1) / 2;                          // 820 upper-tri tiles
    simexp_mfma<<<ntiles, 256, 0, stream>>>(zn, S, pos);
    loss_kernel<<<N_ / 256, 256, 0, stream>>>(S, pos, out);
}